// Round 7
// baseline (551.246 us; speedup 1.0000x reference)
//
#include <hip/hip_runtime.h>
#include <stdint.h>

typedef unsigned short u16;
typedef __bf16 v8bf __attribute__((ext_vector_type(8)));
typedef float f32x4 __attribute__((ext_vector_type(4)));

#define MFMA16(a, b, c) __builtin_amdgcn_mfma_f32_16x16x32_bf16((a), (b), (c), 0, 0, 0)

typedef const __attribute__((address_space(1))) uint32_t* gp32;
typedef __attribute__((address_space(3))) uint32_t* lp32;
#define ASYNC16(g, l) __builtin_amdgcn_global_load_lds((gp32)(const void*)(g), (lp32)(void*)(l), 16, 0, 0)

__device__ __forceinline__ u16 f2bf(float f) {
  union { float f; uint32_t u; } v; v.f = f;
  uint32_t r = v.u + 0x7fffu + ((v.u >> 16) & 1u);
  return (u16)(r >> 16);
}
__device__ __forceinline__ float bf2f(u16 h) {
  union { uint32_t u; float f; } v; v.u = ((uint32_t)h) << 16;
  return v.f;
}

// Swizzled index into a tile with 128B rows (8 chunks of 16B)
__device__ __forceinline__ int swV(int r, int lc) {
  return r * 64 + (((lc ^ (r & 7)) & 7) << 3);
}

// ---------------- fused prep: cast x + transpose Wa + transpose Wp ----------------
__device__ __forceinline__ void transpose_tile(const float* __restrict__ in,
                                               u16* __restrict__ out, int R, int Cc,
                                               int bx, int by, int tid,
                                               u16 (*tile)[34]) {
  int c0 = bx * 32, r0 = by * 32;
  int tx = tid & 31, ty = tid >> 5;
#pragma unroll
  for (int i = 0; i < 32; i += 8)
    tile[ty + i][tx] = f2bf(in[(size_t)(r0 + ty + i) * Cc + c0 + tx]);
  __syncthreads();
#pragma unroll
  for (int i = 0; i < 32; i += 8)
    out[(size_t)(c0 + ty + i) * R + r0 + tx] = tile[tx][ty + i];
}

__global__ __launch_bounds__(256) void prep_kernel(const float* __restrict__ x,
                                                   u16* __restrict__ xb,
                                                   const float* __restrict__ Wa,
                                                   u16* __restrict__ WaT,
                                                   const float* __restrict__ Wp,
                                                   u16* __restrict__ WpT) {
  __shared__ u16 tile[32][34];
  int bid = blockIdx.x;
  int tid = threadIdx.x;
  if (bid < 4096) {
    int i = (bid * 256 + tid) * 8;
    float4 a = *(const float4*)(x + i);
    float4 b = *(const float4*)(x + i + 4);
    uint4 o;
    o.x = (uint32_t)f2bf(a.x) | ((uint32_t)f2bf(a.y) << 16);
    o.y = (uint32_t)f2bf(a.z) | ((uint32_t)f2bf(a.w) << 16);
    o.z = (uint32_t)f2bf(b.x) | ((uint32_t)f2bf(b.y) << 16);
    o.w = (uint32_t)f2bf(b.z) | ((uint32_t)f2bf(b.w) << 16);
    *(uint4*)(xb + i) = o;
  } else if (bid < 4096 + 12288) {
    int t = bid - 4096;  // Wa: 2048 x 6144 -> 192 x 64 tiles
    transpose_tile(Wa, WaT, 2048, 6144, t % 192, t / 192, tid, tile);
  } else {
    int t = bid - 16384;  // Wp: 2048 x 2048 -> 64 x 64 tiles
    transpose_tile(Wp, WpT, 2048, 2048, t & 63, t >> 6, tid, tile);
  }
}

// ------------- GEMM (m97 pattern, verified): C[M][N] = A[M][K] * Bt[N][K]^T -------------
// 256 threads, 128x128 tile, >2 blocks/CU resident so cross-block wave overlap
// hides the per-tile barrier drain (m114). Used for the proj GEMM.
template <typename OutT>
__global__ __launch_bounds__(256) void gemm_bt(const u16* __restrict__ A,
                                               const u16* __restrict__ Bt,
                                               OutT* __restrict__ C, int M, int N, int K) {
  __shared__ u16 As[128 * 64];
  __shared__ u16 Bs[128 * 64];
  int tid = threadIdx.x;
  int wave = tid >> 6, lane = tid & 63, quad = lane >> 4, l16 = lane & 15;
  int wr = wave >> 1, wc = wave & 1;
  int m0 = blockIdx.y * 128, n0 = blockIdx.x * 128;
  f32x4 acc[4][4] = {};
  int lrow = lane >> 3, lk = lane & 7;
  int lc = lk ^ lrow;
  const u16* Ab = A + (size_t)m0 * K;
  const u16* Bb = Bt + (size_t)n0 * K;

  for (int k0 = 0; k0 < K; k0 += 64) {
#pragma unroll
    for (int j = 0; j < 4; ++j) {
      int rbase = wave * 32 + j * 8;
      int row = rbase + lrow;
      ASYNC16(Ab + (size_t)row * K + k0 + lc * 8, &As[rbase * 64]);
      ASYNC16(Bb + (size_t)row * K + k0 + lc * 8, &Bs[rbase * 64]);
    }
    __syncthreads();
#pragma unroll
    for (int ks = 0; ks < 2; ++ks) {
      v8bf af[4], bfr[4];
#pragma unroll
      for (int t = 0; t < 4; ++t) {
        af[t]  = *(const v8bf*)&As[swV(wr * 64 + t * 16 + l16, ks * 4 + quad)];
        bfr[t] = *(const v8bf*)&Bs[swV(wc * 64 + t * 16 + l16, ks * 4 + quad)];
      }
#pragma unroll
      for (int mt = 0; mt < 4; ++mt)
#pragma unroll
        for (int nt = 0; nt < 4; ++nt)
          acc[mt][nt] = MFMA16(af[mt], bfr[nt], acc[mt][nt]);
    }
    __syncthreads();
  }
#pragma unroll
  for (int mt = 0; mt < 4; ++mt)
#pragma unroll
    for (int nt = 0; nt < 4; ++nt) {
      int row = m0 + wr * 64 + mt * 16 + quad * 4;
      int col = n0 + wc * 64 + nt * 16 + l16;
#pragma unroll
      for (int r = 0; r < 4; ++r) {
        float v = acc[mt][nt][r];
        if constexpr (sizeof(OutT) == 2)
          C[(size_t)(row + r) * N + col] = (OutT)f2bf(v);
        else
          C[(size_t)(row + r) * N + col] = v;
      }
    }
}

// ------------- QKV GEMM with fused RoPE/repack epilogue (verified r6) -------------
__global__ __launch_bounds__(256) void gemm_qkv_rope(const u16* __restrict__ A,
                                                     const u16* __restrict__ Bt,
                                                     const float* __restrict__ cosp,
                                                     const float* __restrict__ sinp,
                                                     u16* __restrict__ qh,
                                                     u16* __restrict__ kh,
                                                     u16* __restrict__ vt) {
  const int K = 2048, T = 2048;
  __shared__ u16 smem[128 * 130];
  u16* As = smem;
  u16* Bs = smem + 128 * 64;
  int tid = threadIdx.x;
  int wave = tid >> 6, lane = tid & 63, quad = lane >> 4, l16 = lane & 15;
  int wr = wave >> 1, wc = wave & 1;
  int m0 = blockIdx.y * 128, n0 = blockIdx.x * 128;
  f32x4 acc[4][4] = {};
  int lrow = lane >> 3, lk = lane & 7;
  int lc = lk ^ lrow;
  const u16* Ab = A + (size_t)m0 * K;
  const u16* Bb = Bt + (size_t)n0 * K;

  for (int k0 = 0; k0 < K; k0 += 64) {
#pragma unroll
    for (int j = 0; j < 4; ++j) {
      int rbase = wave * 32 + j * 8;
      int row = rbase + lrow;
      ASYNC16(Ab + (size_t)row * K + k0 + lc * 8, &As[rbase * 64]);
      ASYNC16(Bb + (size_t)row * K + k0 + lc * 8, &Bs[rbase * 64]);
    }
    __syncthreads();
#pragma unroll
    for (int ks = 0; ks < 2; ++ks) {
      v8bf af[4], bfr[4];
#pragma unroll
      for (int t = 0; t < 4; ++t) {
        af[t]  = *(const v8bf*)&As[swV(wr * 64 + t * 16 + l16, ks * 4 + quad)];
        bfr[t] = *(const v8bf*)&Bs[swV(wc * 64 + t * 16 + l16, ks * 4 + quad)];
      }
#pragma unroll
      for (int mt = 0; mt < 4; ++mt)
#pragma unroll
        for (int nt = 0; nt < 4; ++nt)
          acc[mt][nt] = MFMA16(af[mt], bfr[nt], acc[mt][nt]);
    }
    __syncthreads();  // last iter: all As/Bs reads fenced -> smem reusable
  }

  // stage acc as bf16 into LDS tile [128][130]
#pragma unroll
  for (int mt = 0; mt < 4; ++mt)
#pragma unroll
    for (int nt = 0; nt < 4; ++nt) {
      int rloc = wr * 64 + mt * 16 + quad * 4;
      int cloc = wc * 64 + nt * 16 + l16;
#pragma unroll
      for (int r = 0; r < 4; ++r)
        smem[(rloc + r) * 130 + cloc] = f2bf(acc[mt][nt][r]);
    }
  __syncthreads();

  int sec = (int)blockIdx.x >> 4;  // 0=q 1=k 2=v
  int h   = (int)blockIdx.x & 15;
  int b   = m0 >> 11;
  int t0  = m0 & 2047;
  int bh  = b * 16 + h;

  if (sec < 2) {
    u16* dst = sec ? kh : qh;
    const float QSCL = 0.08838834764831845f * 1.4426950408889634f;
    float scl = sec ? 1.0f : QSCL;
    int j = tid & 63, tl0 = tid >> 6;
#pragma unroll 4
    for (int i = 0; i < 32; ++i) {
      int tl = i * 4 + tl0;
      int t  = t0 + tl;
      float c = cosp[t * 64 + j], s = sinp[t * 64 + j];
      float x1 = bf2f(smem[tl * 130 + j]);
      float x2 = bf2f(smem[tl * 130 + 64 + j]);
      size_t o = ((size_t)bh * T + t) * 128;
      dst[o + j]      = f2bf((x1 * c - x2 * s) * scl);
      dst[o + 64 + j] = f2bf((x1 * s + x2 * c) * scl);
    }
  } else {
    int l = tid & 63, w = tid >> 6;
#pragma unroll 4
    for (int i = 0; i < 32; ++i) {
      int d = i * 4 + w;
      size_t o = ((size_t)bh * 128 + d) * T + t0;
      vt[o + l]      = smem[l * 130 + d];
      vt[o + 64 + l] = smem[(64 + l) * 130 + d];
    }
  }
}

// ------------- Flash attention, no LDS staging, no barriers -------------
// K/V are L2/L3-resident (kh+vt = 32MB; 1MB per bh, shared by 16 q-tile
// blocks) and a kv-iteration's K-tile (16KB) + V-tile (16KB) fit L1, so LDS
// staging is pure overhead (Common-mistake #7 / m169). K and V fragments are
// read DIRECTLY from global inside the MFMA loops - bit-identical values to
// the old swizzled-LDS reads (kf: row kv0+nt*16+l16, d-chunk ks*32+quad*8;
// vf: row dt*16+l16, kv-chunk kv0+ks*32+quad*8; 16B/lane, 64B/row chunks).
// Pb is wave-private (rows wave*16..+15) and the ds_write->ds_read path is
// same-wave lgkm-ordered (proven in r5: no barrier between P write and PV
// read), so the main loop has ZERO barriers - waves run fully independent.
// LDS 80KB -> 16KB, so q-tile pairs split into single-qt blocks: grid (16,32)
// = 512 blocks = 2 blocks/CU = 4 waves/SIMD. Complementary-length mapping
// qt = (by<16) ? 15-bx : bx makes any CU pairing of block c with c+256 sum
// to 34 iters (pairing-proof load balance).
__global__ __launch_bounds__(512) void flash_attn(const u16* __restrict__ qh,
                                                  const u16* __restrict__ kh,
                                                  const u16* __restrict__ vt,
                                                  u16* __restrict__ yh) {
  __shared__ u16 Pb[128 * 64];  // [q][kv] swizzled 8-chunk rows, wave-private regions
  const int T = 2048, HD = 128;
  int tid = threadIdx.x;
  int wave = tid >> 6, lane = tid & 63, quad = lane >> 4, l16 = lane & 15;
  int bh = blockIdx.y, b = bh >> 4, h = bh & 15;
  const u16* qb = qh + (size_t)bh * T * HD;
  const u16* kb = kh + (size_t)bh * T * HD;
  const u16* vb = vt + (size_t)bh * HD * T;

  int qt = (bh < 16) ? 15 - (int)blockIdx.x : (int)blockIdx.x;
  int q0 = qt * 128;
  int n_it = 2 * qt + 2;

  // q fragments (pre-scaled by scale*log2e); wave owns rows q0+wave*16..+15
  v8bf qf[4];
#pragma unroll
  for (int ks = 0; ks < 4; ++ks)
    qf[ks] = *(const v8bf*)&qb[(size_t)(q0 + wave * 16 + l16) * HD + ks * 32 + quad * 8];

  f32x4 acc[8] = {};
  float rs_p[4] = {};  // per-lane softmax-denominator partials

  for (int it = 0; it < n_it; ++it) {
    int kv0 = it * 64;

    // S = q . k^T  (K direct from global, L1/L2-served)
    f32x4 s[4] = {};
#pragma unroll
    for (int ks = 0; ks < 4; ++ks)
#pragma unroll
      for (int nt = 0; nt < 4; ++nt) {
        v8bf kf = *(const v8bf*)&kb[(size_t)(kv0 + nt * 16 + l16) * HD + ks * 32 + quad * 8];
        s[nt] = MFMA16(qf[ks], kf, s[nt]);
      }

    if (it >= 2 * qt) {  // diagonal: causal mask
#pragma unroll
      for (int r = 0; r < 4; ++r) {
        int row = q0 + wave * 16 + quad * 4 + r;
#pragma unroll
        for (int nt = 0; nt < 4; ++nt)
          if (kv0 + nt * 16 + l16 > row) s[nt][r] = -1e30f;
      }
    }

    // p = exp2(s), accumulate denominator partial, write P (wave-private LDS)
#pragma unroll
    for (int nt = 0; nt < 4; ++nt)
#pragma unroll
      for (int r = 0; r < 4; ++r) {
        float p = __builtin_exp2f(s[nt][r]);
        rs_p[r] += p;
        int row = wave * 16 + quad * 4 + r;
        int col = nt * 16 + l16;
        Pb[row * 64 + ((((col >> 3) ^ (row & 7)) & 7) << 3) + (col & 7)] = f2bf(p);
      }

    // O += P . V  (V direct from global, L1/L2-served)
#pragma unroll
    for (int ks = 0; ks < 2; ++ks) {
      v8bf pa = *(const v8bf*)&Pb[swV(wave * 16 + l16, ks * 4 + quad)];
#pragma unroll
      for (int dt = 0; dt < 8; ++dt) {
        v8bf vf = *(const v8bf*)&vb[(size_t)(dt * 16 + l16) * T + kv0 + ks * 32 + quad * 8];
        acc[dt] = MFMA16(pa, vf, acc[dt]);
      }
    }
  }

  // epilogue: reduce denominator over the 16 kv-lanes (within quad), store
#pragma unroll
  for (int r = 0; r < 4; ++r) {
    float rsv = rs_p[r];
    rsv += __shfl_xor(rsv, 1);
    rsv += __shfl_xor(rsv, 2);
    rsv += __shfl_xor(rsv, 4);
    rsv += __shfl_xor(rsv, 8);
    float inv = 1.f / rsv;
    int t = q0 + wave * 16 + quad * 4 + r;
#pragma unroll
    for (int dt = 0; dt < 8; ++dt)
      yh[(size_t)(b * T + t) * 2048 + h * 128 + dt * 16 + l16] = f2bf(acc[dt][r] * inv);
  }
}

// ---------------- launch ----------------
extern "C" void kernel_launch(void* const* d_in, const int* in_sizes, int n_in,
                              void* d_out, int out_size, void* d_ws, size_t ws_size,
                              hipStream_t stream) {
  const float* x    = (const float*)d_in[0];
  const float* cosp = (const float*)d_in[1];
  const float* sinp = (const float*)d_in[2];
  const float* Wa   = (const float*)d_in[3];
  const float* Wp   = (const float*)d_in[4];
  float* out = (float*)d_out;

  char* ws = (char*)d_ws;
  u16* xb  = (u16*)(ws);                          // 16 MB
  u16* WaT = (u16*)(ws + (size_t)(16 << 20));     // 24 MB
  u16* WpT = (u16*)(ws + (size_t)(40 << 20));     //  8 MB
  u16* qh  = (u16*)(ws + (size_t)(48 << 20));     // 16 MB
  u16* kh  = (u16*)(ws + (size_t)(64 << 20));     // 16 MB
  u16* vt  = (u16*)(ws + (size_t)(80 << 20));     // 16 MB
  u16* yh  = (u16*)(ws + (size_t)(96 << 20));     // 16 MB

  prep_kernel<<<20480, 256, 0, stream>>>(x, xb, Wa, WaT, Wp, WpT);
  gemm_qkv_rope<<<dim3(48, 32), 256, 0, stream>>>(xb, WaT, cosp, sinp, qh, kh, vt);
  flash_attn<<<dim3(16, 32), 512, 0, stream>>>(qh, kh, vt, yh);
  gemm_bt<float><<<dim3(16, 32), 256, 0, stream>>>(yh, WpT, out, 4096, 2048, 2048);
}

// Round 8
// 391.406 us; speedup vs baseline: 1.4084x; 1.4084x over previous
//
#include <hip/hip_runtime.h>
#include <stdint.h>

typedef unsigned short u16;
typedef __bf16 v8bf __attribute__((ext_vector_type(8)));
typedef float f32x4 __attribute__((ext_vector_type(4)));

#define MFMA16(a, b, c) __builtin_amdgcn_mfma_f32_16x16x32_bf16((a), (b), (c), 0, 0, 0)

typedef const __attribute__((address_space(1))) uint32_t* gp32;
typedef __attribute__((address_space(3))) uint32_t* lp32;
#define ASYNC16(g, l) __builtin_amdgcn_global_load_lds((gp32)(const void*)(g), (lp32)(void*)(l), 16, 0, 0)

__device__ __forceinline__ u16 f2bf(float f) {
  union { float f; uint32_t u; } v; v.f = f;
  uint32_t r = v.u + 0x7fffu + ((v.u >> 16) & 1u);
  return (u16)(r >> 16);
}
__device__ __forceinline__ float bf2f(u16 h) {
  union { uint32_t u; float f; } v; v.u = ((uint32_t)h) << 16;
  return v.f;
}

// Swizzled index into a tile with 256B rows (16 chunks of 16B): phys chunk = lc ^ (r&7)
__device__ __forceinline__ int swK(int r, int lc) {
  return r * 128 + (((lc ^ (r & 7)) & 15) << 3);
}
// Swizzled index into a tile with 128B rows (8 chunks of 16B)
__device__ __forceinline__ int swV(int r, int lc) {
  return r * 64 + (((lc ^ (r & 7)) & 7) << 3);
}

// ---------------- fused prep: cast x + transpose Wa + transpose Wp ----------------
__device__ __forceinline__ void transpose_tile(const float* __restrict__ in,
                                               u16* __restrict__ out, int R, int Cc,
                                               int bx, int by, int tid,
                                               u16 (*tile)[34]) {
  int c0 = bx * 32, r0 = by * 32;
  int tx = tid & 31, ty = tid >> 5;
#pragma unroll
  for (int i = 0; i < 32; i += 8)
    tile[ty + i][tx] = f2bf(in[(size_t)(r0 + ty + i) * Cc + c0 + tx]);
  __syncthreads();
#pragma unroll
  for (int i = 0; i < 32; i += 8)
    out[(size_t)(c0 + ty + i) * R + r0 + tx] = tile[tx][ty + i];
}

__global__ __launch_bounds__(256) void prep_kernel(const float* __restrict__ x,
                                                   u16* __restrict__ xb,
                                                   const float* __restrict__ Wa,
                                                   u16* __restrict__ WaT,
                                                   const float* __restrict__ Wp,
                                                   u16* __restrict__ WpT) {
  __shared__ u16 tile[32][34];
  int bid = blockIdx.x;
  int tid = threadIdx.x;
  if (bid < 4096) {
    int i = (bid * 256 + tid) * 8;
    float4 a = *(const float4*)(x + i);
    float4 b = *(const float4*)(x + i + 4);
    uint4 o;
    o.x = (uint32_t)f2bf(a.x) | ((uint32_t)f2bf(a.y) << 16);
    o.y = (uint32_t)f2bf(a.z) | ((uint32_t)f2bf(a.w) << 16);
    o.z = (uint32_t)f2bf(b.x) | ((uint32_t)f2bf(b.y) << 16);
    o.w = (uint32_t)f2bf(b.z) | ((uint32_t)f2bf(b.w) << 16);
    *(uint4*)(xb + i) = o;
  } else if (bid < 4096 + 12288) {
    int t = bid - 4096;  // Wa: 2048 x 6144 -> 192 x 64 tiles
    transpose_tile(Wa, WaT, 2048, 6144, t % 192, t / 192, tid, tile);
  } else {
    int t = bid - 16384;  // Wp: 2048 x 2048 -> 64 x 64 tiles
    transpose_tile(Wp, WpT, 2048, 2048, t & 63, t >> 6, tid, tile);
  }
}

// ------------- GEMM (m97 pattern, verified): C[M][N] = A[M][K] * Bt[N][K]^T -------------
// 256 threads, 128x128 tile, >2 blocks/CU resident so cross-block wave overlap
// hides the per-tile barrier drain (m114). Used for the proj GEMM.
template <typename OutT>
__global__ __launch_bounds__(256) void gemm_bt(const u16* __restrict__ A,
                                               const u16* __restrict__ Bt,
                                               OutT* __restrict__ C, int M, int N, int K) {
  __shared__ u16 As[128 * 64];
  __shared__ u16 Bs[128 * 64];
  int tid = threadIdx.x;
  int wave = tid >> 6, lane = tid & 63, quad = lane >> 4, l16 = lane & 15;
  int wr = wave >> 1, wc = wave & 1;
  int m0 = blockIdx.y * 128, n0 = blockIdx.x * 128;
  f32x4 acc[4][4] = {};
  int lrow = lane >> 3, lk = lane & 7;
  int lc = lk ^ lrow;
  const u16* Ab = A + (size_t)m0 * K;
  const u16* Bb = Bt + (size_t)n0 * K;

  for (int k0 = 0; k0 < K; k0 += 64) {
#pragma unroll
    for (int j = 0; j < 4; ++j) {
      int rbase = wave * 32 + j * 8;
      int row = rbase + lrow;
      ASYNC16(Ab + (size_t)row * K + k0 + lc * 8, &As[rbase * 64]);
      ASYNC16(Bb + (size_t)row * K + k0 + lc * 8, &Bs[rbase * 64]);
    }
    __syncthreads();
#pragma unroll
    for (int ks = 0; ks < 2; ++ks) {
      v8bf af[4], bfr[4];
#pragma unroll
      for (int t = 0; t < 4; ++t) {
        af[t]  = *(const v8bf*)&As[swV(wr * 64 + t * 16 + l16, ks * 4 + quad)];
        bfr[t] = *(const v8bf*)&Bs[swV(wc * 64 + t * 16 + l16, ks * 4 + quad)];
      }
#pragma unroll
      for (int mt = 0; mt < 4; ++mt)
#pragma unroll
        for (int nt = 0; nt < 4; ++nt)
          acc[mt][nt] = MFMA16(af[mt], bfr[nt], acc[mt][nt]);
    }
    __syncthreads();
  }
#pragma unroll
  for (int mt = 0; mt < 4; ++mt)
#pragma unroll
    for (int nt = 0; nt < 4; ++nt) {
      int row = m0 + wr * 64 + mt * 16 + quad * 4;
      int col = n0 + wc * 64 + nt * 16 + l16;
#pragma unroll
      for (int r = 0; r < 4; ++r) {
        float v = acc[mt][nt][r];
        if constexpr (sizeof(OutT) == 2)
          C[(size_t)(row + r) * N + col] = (OutT)f2bf(v);
        else
          C[(size_t)(row + r) * N + col] = v;
      }
    }
}

// ------------- QKV GEMM with fused RoPE/repack epilogue (verified r6) -------------
__global__ __launch_bounds__(256) void gemm_qkv_rope(const u16* __restrict__ A,
                                                     const u16* __restrict__ Bt,
                                                     const float* __restrict__ cosp,
                                                     const float* __restrict__ sinp,
                                                     u16* __restrict__ qh,
                                                     u16* __restrict__ kh,
                                                     u16* __restrict__ vt) {
  const int K = 2048, T = 2048;
  __shared__ u16 smem[128 * 130];
  u16* As = smem;
  u16* Bs = smem + 128 * 64;
  int tid = threadIdx.x;
  int wave = tid >> 6, lane = tid & 63, quad = lane >> 4, l16 = lane & 15;
  int wr = wave >> 1, wc = wave & 1;
  int m0 = blockIdx.y * 128, n0 = blockIdx.x * 128;
  f32x4 acc[4][4] = {};
  int lrow = lane >> 3, lk = lane & 7;
  int lc = lk ^ lrow;
  const u16* Ab = A + (size_t)m0 * K;
  const u16* Bb = Bt + (size_t)n0 * K;

  for (int k0 = 0; k0 < K; k0 += 64) {
#pragma unroll
    for (int j = 0; j < 4; ++j) {
      int rbase = wave * 32 + j * 8;
      int row = rbase + lrow;
      ASYNC16(Ab + (size_t)row * K + k0 + lc * 8, &As[rbase * 64]);
      ASYNC16(Bb + (size_t)row * K + k0 + lc * 8, &Bs[rbase * 64]);
    }
    __syncthreads();
#pragma unroll
    for (int ks = 0; ks < 2; ++ks) {
      v8bf af[4], bfr[4];
#pragma unroll
      for (int t = 0; t < 4; ++t) {
        af[t]  = *(const v8bf*)&As[swV(wr * 64 + t * 16 + l16, ks * 4 + quad)];
        bfr[t] = *(const v8bf*)&Bs[swV(wc * 64 + t * 16 + l16, ks * 4 + quad)];
      }
#pragma unroll
      for (int mt = 0; mt < 4; ++mt)
#pragma unroll
        for (int nt = 0; nt < 4; ++nt)
          acc[mt][nt] = MFMA16(af[mt], bfr[nt], acc[mt][nt]);
    }
    __syncthreads();  // last iter: all As/Bs reads fenced -> smem reusable
  }

  // stage acc as bf16 into LDS tile [128][130]
#pragma unroll
  for (int mt = 0; mt < 4; ++mt)
#pragma unroll
    for (int nt = 0; nt < 4; ++nt) {
      int rloc = wr * 64 + mt * 16 + quad * 4;
      int cloc = wc * 64 + nt * 16 + l16;
#pragma unroll
      for (int r = 0; r < 4; ++r)
        smem[(rloc + r) * 130 + cloc] = f2bf(acc[mt][nt][r]);
    }
  __syncthreads();

  int sec = (int)blockIdx.x >> 4;  // 0=q 1=k 2=v
  int h   = (int)blockIdx.x & 15;
  int b   = m0 >> 11;
  int t0  = m0 & 2047;
  int bh  = b * 16 + h;

  if (sec < 2) {
    u16* dst = sec ? kh : qh;
    const float QSCL = 0.08838834764831845f * 1.4426950408889634f;
    float scl = sec ? 1.0f : QSCL;
    int j = tid & 63, tl0 = tid >> 6;
#pragma unroll 4
    for (int i = 0; i < 32; ++i) {
      int tl = i * 4 + tl0;
      int t  = t0 + tl;
      float c = cosp[t * 64 + j], s = sinp[t * 64 + j];
      float x1 = bf2f(smem[tl * 130 + j]);
      float x2 = bf2f(smem[tl * 130 + 64 + j]);
      size_t o = ((size_t)bh * T + t) * 128;
      dst[o + j]      = f2bf((x1 * c - x2 * s) * scl);
      dst[o + 64 + j] = f2bf((x1 * s + x2 * c) * scl);
    }
  } else {
    int l = tid & 63, w = tid >> 6;
#pragma unroll 4
    for (int i = 0; i < 32; ++i) {
      int d = i * 4 + w;
      size_t o = ((size_t)bh * 128 + d) * T + t0;
      vt[o + l]      = smem[l * 130 + d];
      vt[o + 64 + l] = smem[(64 + l) * 130 + d];
    }
  }
}

// ------------- Pipelined flash attention, 1 barrier/iter, 2 blocks/CU -------------
// r5-verified loop structure (dbuf K via ASYNC prefetch, dbuf V via reg
// prefetch, single end-of-iter barrier fencing [1-c] writes vs [c] reads)
// with q-tile PAIRS split into single-qt blocks. Splitting the pair adds NO
// staging duplication (total staged tiles = sum(2qt+2) = 34 per pair either
// way - r4's regression came from halving q-rows, not splitting the pair).
// Grid (16,32) = 512 blocks, 512 thr, 80KB LDS; 2x80KB = exactly 160KiB so
// TWO blocks co-reside per CU (16 waves/CU, 4 waves/SIMD - double r5). Their
// barriers are independent: one block's MFMA covers the other's vmcnt/barrier
// drain (m114 - the mechanism behind every win this session).
// __launch_bounds__(512,4) caps VGPR at 128 so registers don't block the
// second block (live state ~56 VGPRs). Balance: qt=(bh<16)?15-bx:bx pairs
// block c with c+256 (same CU slot) at complementary lengths -> 34 iters/CU.
__global__ __launch_bounds__(512, 4) void flash_attn(const u16* __restrict__ qh,
                                                     const u16* __restrict__ kh,
                                                     const u16* __restrict__ vt,
                                                     u16* __restrict__ yh) {
  __shared__ u16 Ks[2][64 * 128];  // [buf][kv][d] swizzled 16-chunk rows
  __shared__ u16 Vs[2][128 * 64];  // [buf][d][kv] swizzled 8-chunk rows
  __shared__ u16 Pb[128 * 64];     // [q][kv]      swizzled 8-chunk rows
  const int T = 2048, HD = 128;
  int tid = threadIdx.x;
  int wave = tid >> 6, lane = tid & 63, quad = lane >> 4, l16 = lane & 15;
  int bh = blockIdx.y, b = bh >> 4, h = bh & 15;
  const u16* qb = qh + (size_t)bh * T * HD;
  const u16* kb = kh + (size_t)bh * T * HD;
  const u16* vb = vt + (size_t)bh * HD * T;
  int krow_off = lane >> 4, kchunk = lane & 15;
  int vrow_off = lane >> 3, vchunk = lane & 7;

  int qt = (bh < 16) ? 15 - (int)blockIdx.x : (int)blockIdx.x;
  int q0 = qt * 128;
  int n_it = 2 * qt + 2;

  // q fragments (pre-scaled by scale*log2e); each wave owns rows q0+wave*16..+15
  v8bf qf[4];
#pragma unroll
  for (int ks = 0; ks < 4; ++ks)
    qf[ks] = *(const v8bf*)&qb[(size_t)(q0 + wave * 16 + l16) * HD + ks * 32 + quad * 8];

  f32x4 acc[8] = {};
  float rs_p[4] = {};  // per-lane softmax-denominator partials
  uint4 vreg[2];

  // prologue: stage K(0) async into Ks[0], V(0) regs -> commit Vs[0], one barrier
#pragma unroll
  for (int j = 0; j < 2; ++j) {
    int rbase = wave * 8 + j * 4;
    int r = rbase + krow_off;
    int lc = kchunk ^ (r & 7);
    ASYNC16(kb + (size_t)r * HD + lc * 8, &Ks[0][rbase * 128]);
  }
#pragma unroll
  for (int j = 0; j < 2; ++j) {
    int row = wave * 16 + j * 8 + vrow_off;
    int lc = vchunk ^ (row & 7);
    vreg[j] = *(const uint4*)&vb[(size_t)row * T + lc * 8];
  }
#pragma unroll
  for (int j = 0; j < 2; ++j) {
    int row = wave * 16 + j * 8 + vrow_off;
    *(uint4*)&Vs[0][row * 64 + vchunk * 8] = vreg[j];
  }
  __syncthreads();  // K(0) landed + V(0) committed

  for (int it = 0; it < n_it; ++it) {
    int c = it & 1;

    if (it + 1 < n_it) {  // issue prefetch of tile it+1 into buffers [1-c]
      int kv0n = (it + 1) * 64;
#pragma unroll
      for (int j = 0; j < 2; ++j) {
        int rbase = wave * 8 + j * 4;
        int r = rbase + krow_off;
        int lc = kchunk ^ (r & 7);
        ASYNC16(kb + (size_t)(kv0n + r) * HD + lc * 8, &Ks[1 - c][rbase * 128]);
      }
#pragma unroll
      for (int j = 0; j < 2; ++j) {
        int row = wave * 16 + j * 8 + vrow_off;
        int lc = vchunk ^ (row & 7);
        vreg[j] = *(const uint4*)&vb[(size_t)row * T + kv0n + lc * 8];
      }
    }

    // S = q . k^T
    f32x4 s[4] = {};
#pragma unroll
    for (int ks = 0; ks < 4; ++ks)
#pragma unroll
      for (int nt = 0; nt < 4; ++nt) {
        v8bf kf = *(const v8bf*)&Ks[c][swK(nt * 16 + l16, ks * 4 + quad)];
        s[nt] = MFMA16(qf[ks], kf, s[nt]);
      }

    if (it >= 2 * qt) {  // diagonal: causal mask
      int kv0 = it * 64;
#pragma unroll
      for (int r = 0; r < 4; ++r) {
        int row = q0 + wave * 16 + quad * 4 + r;
#pragma unroll
        for (int nt = 0; nt < 4; ++nt)
          if (kv0 + nt * 16 + l16 > row) s[nt][r] = -1e30f;
      }
    }

    // p = exp2(s), accumulate denominator partial, write P
#pragma unroll
    for (int nt = 0; nt < 4; ++nt)
#pragma unroll
      for (int r = 0; r < 4; ++r) {
        float p = __builtin_exp2f(s[nt][r]);
        rs_p[r] += p;
        int row = wave * 16 + quad * 4 + r;
        int col = nt * 16 + l16;
        Pb[row * 64 + ((((col >> 3) ^ (row & 7)) & 7) << 3) + (col & 7)] = f2bf(p);
      }

    // O += P . V  (reads Vs[c])
#pragma unroll
    for (int ks = 0; ks < 2; ++ks) {
      v8bf pa = *(const v8bf*)&Pb[swV(wave * 16 + l16, ks * 4 + quad)];
#pragma unroll
      for (int dt = 0; dt < 8; ++dt) {
        v8bf vf = *(const v8bf*)&Vs[c][swV(dt * 16 + l16, ks * 4 + quad)];
        acc[dt] = MFMA16(pa, vf, acc[dt]);
      }
    }

    if (it + 1 < n_it) {  // commit V(it+1) into Vs[1-c]
#pragma unroll
      for (int j = 0; j < 2; ++j) {
        int row = wave * 16 + j * 8 + vrow_off;
        *(uint4*)&Vs[1 - c][row * 64 + vchunk * 8] = vreg[j];
      }
    }

    __syncthreads();  // the ONLY barrier: fences [1-c] writes and [c] reads
  }

  // epilogue: reduce denominator over the 16 kv-lanes (within quad), store
#pragma unroll
  for (int r = 0; r < 4; ++r) {
    float rsv = rs_p[r];
    rsv += __shfl_xor(rsv, 1);
    rsv += __shfl_xor(rsv, 2);
    rsv += __shfl_xor(rsv, 4);
    rsv += __shfl_xor(rsv, 8);
    float inv = 1.f / rsv;
    int t = q0 + wave * 16 + quad * 4 + r;
#pragma unroll
    for (int dt = 0; dt < 8; ++dt)
      yh[(size_t)(b * T + t) * 2048 + h * 128 + dt * 16 + l16] = f2bf(acc[dt][r] * inv);
  }
}

// ---------------- launch ----------------
extern "C" void kernel_launch(void* const* d_in, const int* in_sizes, int n_in,
                              void* d_out, int out_size, void* d_ws, size_t ws_size,
                              hipStream_t stream) {
  const float* x    = (const float*)d_in[0];
  const float* cosp = (const float*)d_in[1];
  const float* sinp = (const float*)d_in[2];
  const float* Wa   = (const float*)d_in[3];
  const float* Wp   = (const float*)d_in[4];
  float* out = (float*)d_out;

  char* ws = (char*)d_ws;
  u16* xb  = (u16*)(ws);                          // 16 MB
  u16* WaT = (u16*)(ws + (size_t)(16 << 20));     // 24 MB
  u16* WpT = (u16*)(ws + (size_t)(40 << 20));     //  8 MB
  u16* qh  = (u16*)(ws + (size_t)(48 << 20));     // 16 MB
  u16* kh  = (u16*)(ws + (size_t)(64 << 20));     // 16 MB
  u16* vt  = (u16*)(ws + (size_t)(80 << 20));     // 16 MB
  u16* yh  = (u16*)(ws + (size_t)(96 << 20));     // 16 MB

  prep_kernel<<<20480, 256, 0, stream>>>(x, xb, Wa, WaT, Wp, WpT);
  gemm_qkv_rope<<<dim3(48, 32), 256, 0, stream>>>(xb, WaT, cosp, sinp, qh, kh, vt);
  flash_attn<<<dim3(16, 32), 512, 0, stream>>>(qh, kh, vt, yh);
  gemm_bt<float><<<dim3(16, 32), 256, 0, stream>>>(yh, WpT, out, 4096, 2048, 2048);
}